// Round 13
// baseline (11.357 us; speedup 1.0000x reference)
//
#include <hip/hip_runtime.h>
#include <math.h>

#define BATCH 8
#define NTR   1024   // tracks per batch
// output: [BATCH*NTR, 32], float32

typedef unsigned int v2u __attribute__((ext_vector_type(2)));

// DPP-based partner fetch (compile-time ctrl); works within 16-lane rows
template<int CTRL>
__device__ __forceinline__ float dpp_f(float x) {
    union { float f; int i; } u;
    u.f = x;
    u.i = __builtin_amdgcn_mov_dpp(u.i, CTRL, 0xF, 0xF, false);
    return u.f;
}

// ds_swizzle xor16 (BitMode: xor=16, and=0x1F) — lane^16 within each 32-half
__device__ __forceinline__ float swz16(float x) {
    union { float f; int i; } u;
    u.f = x;
    u.i = __builtin_amdgcn_ds_swizzle(u.i, 0x401F);
    return u.f;
}

// v_permlane32_swap_b32 with both inputs = x:
//   out0: lanes<32 -> own x, lanes>=32 -> partner x[lane-32]
//   out1: lanes<32 -> partner x[lane+32], lanes>=32 -> own x
// partner(lane^32) = (lane>=32) ? out0 : out1   (branchless cndmask select)
__device__ __forceinline__ float pl32_partner(float x, bool hi) {
    union { float f; unsigned u; } a, o0, o1;
    a.f = x;
    v2u r = __builtin_amdgcn_permlane32_swap(a.u, a.u, false, false);
    o0.u = r.x; o1.u = r.y;
    return hi ? o0.f : o1.f;
}

// merge my ascending (s0..s3) with partner's ascending (e0..e3): keep 4 smallest
#define MERGE4(E0, E1, E2, E3)                              \
    {                                                       \
        float m0 = fminf(s0, (E3));                         \
        float m1 = fminf(s1, (E2));                         \
        float m2 = fminf(s2, (E1));                         \
        float m3 = fminf(s3, (E0));                         \
        float a;                                            \
        a = fminf(m0, m2); m2 = fmaxf(m0, m2); m0 = a;      \
        a = fminf(m1, m3); m3 = fmaxf(m1, m3); m1 = a;      \
        a = fminf(m0, m1); m1 = fmaxf(m0, m1); m0 = a;      \
        a = fminf(m2, m3); m3 = fmaxf(m2, m3); m2 = a;      \
        s0 = m0; s1 = m1; s2 = m2; s3 = m3;                 \
    }

__global__ __launch_bounds__(256)
void knn_v13(const float* __restrict__ obs1,
             const float* __restrict__ obs2,
             const float* __restrict__ W,
             const float* __restrict__ bias,
             float* __restrict__ out)
{
    __shared__ __align__(16) float2 sh_pos[NTR];   // obs2[batch] (8 KB)
    __shared__ int sh_idx[4][4];                   // per-wave top-4 indices

    const int tid   = threadIdx.x;
    const int lane  = tid & 63;
    const int wv    = tid >> 6;                    // wave in block: 0..3
    const int batch = blockIdx.x >> 8;             // 256 blocks per batch
    const int i     = ((blockIdx.x & 255) << 2) + wv;   // this wave's row

    // ---- stage obs2 into LDS; keep own two float4s in registers ----
    // sp4[idx] holds tracks 2*idx, 2*idx+1; lane l of wave wv stages
    // idx = 64*wv + l (scan slot wv) and idx+256 (scan slot wv+4).
    const float4* __restrict__ p2 = (const float4*)(obs2 + (size_t)batch * NTR * 2);
    float4* sp4 = (float4*)sh_pos;
    const float4 reg0 = p2[tid];
    const float4 reg4 = p2[tid + 256];
    sp4[tid]       = reg0;
    sp4[tid + 256] = reg4;
    __syncthreads();                               // the ONLY barrier

    const float2 my = sh_pos[i];   // wave-uniform broadcast read

    // self-candidate bookkeeping (slot containing track i, per-lane flags)
    const int  c_self    = i >> 7;                         // 0..7
    const bool self_even = (lane == ((i >> 1) & 63)) && ((i & 1) == 0);
    const bool self_odd  = (lane == ((i >> 1) & 63)) && ((i & 1) == 1);

    // ---- pass 1: slots in order (wv+q)&7; q=0,4 come from registers ----
    float s0 = 3e38f, s1 = 3e38f, s2 = 3e38f, s3 = 3e38f;
    float dd[16];                  // cached squared distances (unrolled -> VGPRs)

    const float4* pos4 = (const float4*)sh_pos;
#pragma unroll
    for (int q = 0; q < 8; ++q) {
        const int slot = (wv + q) & 7;             // wave-uniform
        float4 pq;
        if (q == 0)      pq = reg0;                // compile-time after unroll
        else if (q == 4) pq = reg4;
        else             pq = pos4[(slot << 6) + lane];

        const float dx0 = pq.x - my.x;
        const float dy0 = pq.y - my.y;
        const float dx1 = pq.z - my.x;
        const float dy1 = pq.w - my.y;
        float d0 = __fmaf_rn(dy0, dy0, __fmul_rn(dx0, dx0));
        float d1 = __fmaf_rn(dy1, dy1, __fmul_rn(dx1, dx1));
        if (slot == c_self) {                      // wave-uniform scalar branch
            d0 = self_even ? 3e38f : d0;
            d1 = self_odd  ? 3e38f : d1;
        }
        dd[2 * q]     = d0;
        dd[2 * q + 1] = d1;
        {   // insert d0 into sorted (s0<=s1<=s2<=s3): depth-1 min/med3 network
            const float t0 = fminf(s0, d0);
            const float t1 = __builtin_amdgcn_fmed3f(s0, s1, d0);
            const float t2 = __builtin_amdgcn_fmed3f(s1, s2, d0);
            const float t3 = __builtin_amdgcn_fmed3f(s2, s3, d0);
            s0 = t0; s1 = t1; s2 = t2; s3 = t3;
        }
        {   // insert d1
            const float t0 = fminf(s0, d1);
            const float t1 = __builtin_amdgcn_fmed3f(s0, s1, d1);
            const float t2 = __builtin_amdgcn_fmed3f(s1, s2, d1);
            const float t3 = __builtin_amdgcn_fmed3f(s2, s3, d1);
            s0 = t0; s1 = t1; s2 = t2; s3 = t3;
        }
    }

    // ---- values-only wave merge, fully VALU-side (DPP + swizzle + permlane) ----
    // L1: xor1 = quad_perm [1,0,3,2]
    MERGE4(dpp_f<0xB1>(s0), dpp_f<0xB1>(s1), dpp_f<0xB1>(s2), dpp_f<0xB1>(s3));
    // L2: xor2 = quad_perm [2,3,0,1]
    MERGE4(dpp_f<0x4E>(s0), dpp_f<0x4E>(s1), dpp_f<0x4E>(s2), dpp_f<0x4E>(s3));
    // L4: row_half_mirror (partner quad holds a converged identical list)
    MERGE4(dpp_f<0x141>(s0), dpp_f<0x141>(s1), dpp_f<0x141>(s2), dpp_f<0x141>(s3));
    // L8: row_mirror
    MERGE4(dpp_f<0x140>(s0), dpp_f<0x140>(s1), dpp_f<0x140>(s2), dpp_f<0x140>(s3));
    // L16: ds_swizzle xor16
    MERGE4(swz16(s0), swz16(s1), swz16(s2), swz16(s3));
    // L32: permlane32_swap, explicit partner select (NOT the self-merge trick —
    // merging a list with itself is (s0,s0,s1,s1), not identity; r12's bug)
    {
        const bool hi = (lane >= 32);
        const float e0 = pl32_partner(s0, hi);
        const float e1 = pl32_partner(s1, hi);
        const float e2 = pl32_partner(s2, hi);
        const float e3 = pl32_partner(s3, hi);
        MERGE4(e0, e1, e2, e3);
    }
    // now every lane holds the row's global sorted top-4 in s0..s3

    // ---- pass 2: recover indices from cached dds (exactly 4 hits/row) ----
#pragma unroll
    for (int k = 0; k < 16; ++k) {
        if (dd[k] <= s3) {                        // rare: ~4 of 1024 per row
            const int slot = (wv + (k >> 1)) & 7;
            const int j = (slot << 7) + (lane << 1) + (k & 1);
            const int rank = (int)(dd[k] > s0) + (int)(dd[k] > s1)
                           + (int)(dd[k] > s2);
            sh_idx[wv][rank] = j;
        }
    }
    asm volatile("" ::: "memory");                 // wave-private sh_idx

    // ---- per-wave epilogue: lanes 0..31 write this wave's row (128 B) ----
    if (lane < 32) {
        const int kk = lane >> 3;                  // neighbor rank 0..3
        const int e  = lane & 7;                   // embedding dim 0..7

        int j = sh_idx[wv][kk] & (NTR - 1);        // defensive in-bounds

        const float2 pj  = sh_pos[j];
        const float2* __restrict__ o1 = (const float2*)(obs1 + (size_t)batch * NTR * 2);
        const float2 o1j = o1[j];
        const float2 o1r = o1[i];
        const float f0 = pj.x - my.x;                       // rel_pos.x
        const float f1 = pj.y - my.y;                       // rel_pos.y
        const float f2 = (pj.x - o1j.x) - (my.x - o1r.x);   // rel_dir.x
        const float f3 = (pj.y - o1j.y) - (my.y - o1r.y);   // rel_dir.y

        const float4 w = ((const float4*)W)[e];
        float r = f0 * w.x + f1 * w.y + f2 * w.z + f3 * w.w + bias[e];
        r = fmaxf(r, 0.0f);

        out[(((size_t)(batch * NTR + i)) << 5) + lane] = r;
    }
}

extern "C" void kernel_launch(void* const* d_in, const int* in_sizes, int n_in,
                              void* d_out, int out_size, void* d_ws, size_t ws_size,
                              hipStream_t stream) {
    const float* obs1 = (const float*)d_in[0];
    const float* obs2 = (const float*)d_in[1];
    const float* W    = (const float*)d_in[2];
    const float* bias = (const float*)d_in[3];
    float* out = (float*)d_out;

    const int grid = BATCH * (NTR / 4);   // 2048 blocks, wave per row, 8/CU
    knn_v13<<<grid, 256, 0, stream>>>(obs1, obs2, W, bias, out);
}

// Round 14
// 11.200 us; speedup vs baseline: 1.0140x; 1.0140x over previous
//
#include <hip/hip_runtime.h>
#include <math.h>

#define BATCH 8
#define NTR   1024   // tracks per batch
// output: [BATCH*NTR, 32], float32

// DPP-based partner fetch (compile-time ctrl); works within 16-lane rows
template<int CTRL>
__device__ __forceinline__ float dpp_f(float x) {
    union { float f; int i; } u;
    u.f = x;
    u.i = __builtin_amdgcn_mov_dpp(u.i, CTRL, 0xF, 0xF, false);
    return u.f;
}

// ds_swizzle xor16 (BitMode: xor=16, and=0x1F) — lane^16 within each 32-half
__device__ __forceinline__ float swz16(float x) {
    union { float f; int i; } u;
    u.f = x;
    u.i = __builtin_amdgcn_ds_swizzle(u.i, 0x401F);
    return u.f;
}

// merge my ascending (s0..s3) with partner's ascending (e0..e3): keep 4 smallest
#define MERGE4(E0, E1, E2, E3)                              \
    {                                                       \
        float m0 = fminf(s0, (E3));                         \
        float m1 = fminf(s1, (E2));                         \
        float m2 = fminf(s2, (E1));                         \
        float m3 = fminf(s3, (E0));                         \
        float a;                                            \
        a = fminf(m0, m2); m2 = fmaxf(m0, m2); m0 = a;      \
        a = fminf(m1, m3); m3 = fmaxf(m1, m3); m1 = a;      \
        a = fminf(m0, m1); m1 = fmaxf(m0, m1); m0 = a;      \
        a = fminf(m2, m3); m3 = fmaxf(m2, m3); m2 = a;      \
        s0 = m0; s1 = m1; s2 = m2; s3 = m3;                 \
    }

__global__ __launch_bounds__(256)
void knn_v14(const float* __restrict__ obs1,
             const float* __restrict__ obs2,
             const float* __restrict__ W,
             const float* __restrict__ bias,
             float* __restrict__ out)
{
    __shared__ __align__(16) float2 sh_pos[NTR];   // obs2[batch] (8 KB)
    __shared__ __align__(16) float4 sh_x[256];     // L32 exchange (4 KB)
    __shared__ int sh_idx[4][4];                   // per-wave top-4 indices

    const int tid   = threadIdx.x;
    const int lane  = tid & 63;
    const int wv    = tid >> 6;                    // wave in block: 0..3
    const int batch = blockIdx.x >> 8;             // 256 blocks per batch
    const int i     = ((blockIdx.x & 255) << 2) + wv;   // this wave's row

    // ---- stage obs2 into LDS; keep own two float4s in registers ----
    // sp4[idx] holds tracks 2*idx, 2*idx+1; lane l of wave wv stages
    // idx = 64*wv + l (scan slot wv) and idx+256 (scan slot wv+4).
    const float4* __restrict__ p2 = (const float4*)(obs2 + (size_t)batch * NTR * 2);
    float4* sp4 = (float4*)sh_pos;
    const float4 reg0 = p2[tid];
    const float4 reg4 = p2[tid + 256];
    sp4[tid]       = reg0;
    sp4[tid + 256] = reg4;
    __syncthreads();                               // the ONLY barrier

    const float2 my = sh_pos[i];   // wave-uniform broadcast read

    // self-candidate bookkeeping (slot containing track i, per-lane flags)
    const int  c_self    = i >> 7;                         // 0..7
    const bool self_even = (lane == ((i >> 1) & 63)) && ((i & 1) == 0);
    const bool self_odd  = (lane == ((i >> 1) & 63)) && ((i & 1) == 1);

    // ---- pass 1: slots in order (wv+q)&7; q=0,4 come from registers ----
    float s0 = 3e38f, s1 = 3e38f, s2 = 3e38f, s3 = 3e38f;
    float dd[16];                  // cached squared distances (unrolled -> VGPRs)

    const float4* pos4 = (const float4*)sh_pos;
#pragma unroll
    for (int q = 0; q < 8; ++q) {
        const int slot = (wv + q) & 7;             // wave-uniform
        float4 pq;
        if (q == 0)      pq = reg0;                // compile-time after unroll
        else if (q == 4) pq = reg4;
        else             pq = pos4[(slot << 6) + lane];

        const float dx0 = pq.x - my.x;
        const float dy0 = pq.y - my.y;
        const float dx1 = pq.z - my.x;
        const float dy1 = pq.w - my.y;
        float d0 = __fmaf_rn(dy0, dy0, __fmul_rn(dx0, dx0));
        float d1 = __fmaf_rn(dy1, dy1, __fmul_rn(dx1, dx1));
        if (slot == c_self) {                      // wave-uniform scalar branch
            d0 = self_even ? 3e38f : d0;
            d1 = self_odd  ? 3e38f : d1;
        }
        dd[2 * q]     = d0;
        dd[2 * q + 1] = d1;
        {   // insert d0 into sorted (s0<=s1<=s2<=s3): depth-1 min/med3 network
            const float t0 = fminf(s0, d0);
            const float t1 = __builtin_amdgcn_fmed3f(s0, s1, d0);
            const float t2 = __builtin_amdgcn_fmed3f(s1, s2, d0);
            const float t3 = __builtin_amdgcn_fmed3f(s2, s3, d0);
            s0 = t0; s1 = t1; s2 = t2; s3 = t3;
        }
        {   // insert d1
            const float t0 = fminf(s0, d1);
            const float t1 = __builtin_amdgcn_fmed3f(s0, s1, d1);
            const float t2 = __builtin_amdgcn_fmed3f(s1, s2, d1);
            const float t3 = __builtin_amdgcn_fmed3f(s2, s3, d1);
            s0 = t0; s1 = t1; s2 = t2; s3 = t3;
        }
    }

    // ---- values-only wave merge (DPP + swizzle + 1 LDS exchange level) ----
    // L1: xor1 = quad_perm [1,0,3,2]
    MERGE4(dpp_f<0xB1>(s0), dpp_f<0xB1>(s1), dpp_f<0xB1>(s2), dpp_f<0xB1>(s3));
    // L2: xor2 = quad_perm [2,3,0,1]
    MERGE4(dpp_f<0x4E>(s0), dpp_f<0x4E>(s1), dpp_f<0x4E>(s2), dpp_f<0x4E>(s3));
    // L4: row_half_mirror
    MERGE4(dpp_f<0x141>(s0), dpp_f<0x141>(s1), dpp_f<0x141>(s2), dpp_f<0x141>(s3));
    // L8: row_mirror
    MERGE4(dpp_f<0x140>(s0), dpp_f<0x140>(s1), dpp_f<0x140>(s2), dpp_f<0x140>(s3));
    // L16: ds_swizzle xor16
    MERGE4(swz16(s0), swz16(s1), swz16(s2), swz16(s3));
    // L32: one LDS float4 exchange with lane^32 (intra-wave, fence only) —
    // r11's proven form; cheaper than permlane+cndmask on the serial chain (r13)
    sh_x[tid] = make_float4(s0, s1, s2, s3);
    asm volatile("" ::: "memory");
    {
        const float4 o = sh_x[tid ^ 32];
        MERGE4(o.x, o.y, o.z, o.w);
    }
    // now every lane holds the row's global sorted top-4 in s0..s3

    // ---- pass 2: recover indices from cached dds (exactly 4 hits/row) ----
#pragma unroll
    for (int k = 0; k < 16; ++k) {
        if (dd[k] <= s3) {                        // rare: ~4 of 1024 per row
            const int slot = (wv + (k >> 1)) & 7;
            const int j = (slot << 7) + (lane << 1) + (k & 1);
            const int rank = (int)(dd[k] > s0) + (int)(dd[k] > s1)
                           + (int)(dd[k] > s2);
            sh_idx[wv][rank] = j;
        }
    }
    asm volatile("" ::: "memory");                 // wave-private sh_idx

    // ---- per-wave epilogue: lanes 0..31 write this wave's row (128 B) ----
    if (lane < 32) {
        const int kk = lane >> 3;                  // neighbor rank 0..3
        const int e  = lane & 7;                   // embedding dim 0..7

        int j = sh_idx[wv][kk] & (NTR - 1);        // defensive in-bounds

        const float2 pj  = sh_pos[j];
        const float2* __restrict__ o1 = (const float2*)(obs1 + (size_t)batch * NTR * 2);
        const float2 o1j = o1[j];
        const float2 o1r = o1[i];
        const float f0 = pj.x - my.x;                       // rel_pos.x
        const float f1 = pj.y - my.y;                       // rel_pos.y
        const float f2 = (pj.x - o1j.x) - (my.x - o1r.x);   // rel_dir.x
        const float f3 = (pj.y - o1j.y) - (my.y - o1r.y);   // rel_dir.y

        const float4 w = ((const float4*)W)[e];
        float r = f0 * w.x + f1 * w.y + f2 * w.z + f3 * w.w + bias[e];
        r = fmaxf(r, 0.0f);

        out[(((size_t)(batch * NTR + i)) << 5) + lane] = r;
    }
}

extern "C" void kernel_launch(void* const* d_in, const int* in_sizes, int n_in,
                              void* d_out, int out_size, void* d_ws, size_t ws_size,
                              hipStream_t stream) {
    const float* obs1 = (const float*)d_in[0];
    const float* obs2 = (const float*)d_in[1];
    const float* W    = (const float*)d_in[2];
    const float* bias = (const float*)d_in[3];
    float* out = (float*)d_out;

    const int grid = BATCH * (NTR / 4);   // 2048 blocks, wave per row, 8/CU
    knn_v14<<<grid, 256, 0, stream>>>(obs1, obs2, W, bias, out);
}

// Round 15
// 10.833 us; speedup vs baseline: 1.0484x; 1.0339x over previous
//
#include <hip/hip_runtime.h>
#include <math.h>

#define BATCH 8
#define NTR   1024   // tracks per batch
// output: [BATCH*NTR, 32], float32

// DPP-based partner fetch (compile-time ctrl); works within 16-lane rows
template<int CTRL>
__device__ __forceinline__ float dpp_f(float x) {
    union { float f; int i; } u;
    u.f = x;
    u.i = __builtin_amdgcn_mov_dpp(u.i, CTRL, 0xF, 0xF, false);
    return u.f;
}

// ds_swizzle xor16 (BitMode: xor=16, and=0x1F) — lane^16 within each 32-half
__device__ __forceinline__ float swz16(float x) {
    union { float f; int i; } u;
    u.f = x;
    u.i = __builtin_amdgcn_ds_swizzle(u.i, 0x401F);
    return u.f;
}

// merge my ascending (s0..s3) with partner's ascending (e0..e3): keep 4 smallest
#define MERGE4(E0, E1, E2, E3)                              \
    {                                                       \
        float m0 = fminf(s0, (E3));                         \
        float m1 = fminf(s1, (E2));                         \
        float m2 = fminf(s2, (E1));                         \
        float m3 = fminf(s3, (E0));                         \
        float a;                                            \
        a = fminf(m0, m2); m2 = fmaxf(m0, m2); m0 = a;      \
        a = fminf(m1, m3); m3 = fmaxf(m1, m3); m1 = a;      \
        a = fminf(m0, m1); m1 = fmaxf(m0, m1); m0 = a;      \
        a = fminf(m2, m3); m3 = fmaxf(m2, m3); m2 = a;      \
        s0 = m0; s1 = m1; s2 = m2; s3 = m3;                 \
    }

__global__ __launch_bounds__(256)
void knn_v15(const float* __restrict__ obs1,
             const float* __restrict__ obs2,
             const float* __restrict__ W,
             const float* __restrict__ bias,
             float* __restrict__ out)
{
    __shared__ __align__(16) float2 sh_pos[NTR];   // obs2[batch] (8 KB)
    __shared__ __align__(16) float4 sh_x[256];     // level-32 exchange (4 KB)
    __shared__ int sh_idx[4][4];                   // per-wave top-4 indices

    const int tid   = threadIdx.x;
    const int lane  = tid & 63;
    const int wv    = tid >> 6;                    // wave in block: 0..3
    const int batch = blockIdx.x >> 8;             // 256 blocks per batch
    const int i     = ((blockIdx.x & 255) << 2) + wv;   // this wave's row

    // ---- stage obs2 into LDS (float4 = 2 tracks per op) ----
    const float4* __restrict__ p2 = (const float4*)(obs2 + (size_t)batch * NTR * 2);
    float4* sp4 = (float4*)sh_pos;
    sp4[tid]       = p2[tid];
    sp4[tid + 256] = p2[tid + 256];
    __syncthreads();                               // the ONLY barrier

    const float2 my = sh_pos[i];   // wave-uniform broadcast read

    // self-candidate bookkeeping (wave-uniform iteration, per-lane flags)
    const int  c_self    = i >> 7;                         // 0..7
    const bool self_even = (lane == ((i >> 1) & 63)) && ((i & 1) == 0);
    const bool self_odd  = (lane == ((i >> 1) & 63)) && ((i & 1) == 1);

    // ---- pass 1: 2 candidates per ds_read_b128, min/med3 sorted-4 ----
    float s0 = 3e38f, s1 = 3e38f, s2 = 3e38f, s3 = 3e38f;
    float dd[16];                  // cached squared distances (unrolled -> VGPRs)

    const float4* pos4 = (const float4*)sh_pos;
#pragma unroll
    for (int c = 0; c < 8; ++c) {
        const float4 pq = pos4[(c << 6) + lane];   // tracks 2*(c*64+lane), +1
        const float dx0 = pq.x - my.x;
        const float dy0 = pq.y - my.y;
        const float dx1 = pq.z - my.x;
        const float dy1 = pq.w - my.y;
        float d0 = __fmaf_rn(dy0, dy0, __fmul_rn(dx0, dx0));
        float d1 = __fmaf_rn(dy1, dy1, __fmul_rn(dx1, dx1));
        if (c == c_self) {                         // wave-uniform scalar branch
            d0 = self_even ? 3e38f : d0;
            d1 = self_odd  ? 3e38f : d1;
        }
        dd[2 * c]     = d0;
        dd[2 * c + 1] = d1;
        {   // insert d0 into sorted (s0<=s1<=s2<=s3): depth-1 min/med3 network
            const float t0 = fminf(s0, d0);
            const float t1 = __builtin_amdgcn_fmed3f(s0, s1, d0);
            const float t2 = __builtin_amdgcn_fmed3f(s1, s2, d0);
            const float t3 = __builtin_amdgcn_fmed3f(s2, s3, d0);
            s0 = t0; s1 = t1; s2 = t2; s3 = t3;
        }
        {   // insert d1
            const float t0 = fminf(s0, d1);
            const float t1 = __builtin_amdgcn_fmed3f(s0, s1, d1);
            const float t2 = __builtin_amdgcn_fmed3f(s1, s2, d1);
            const float t3 = __builtin_amdgcn_fmed3f(s2, s3, d1);
            s0 = t0; s1 = t1; s2 = t2; s3 = t3;
        }
    }

    // ---- values-only wave merge, VALU-side (DPP + swizzle + 1 LDS level) ----
    // L1: xor1 = quad_perm [1,0,3,2]
    MERGE4(dpp_f<0xB1>(s0), dpp_f<0xB1>(s1), dpp_f<0xB1>(s2), dpp_f<0xB1>(s3));
    // L2: xor2 = quad_perm [2,3,0,1]
    MERGE4(dpp_f<0x4E>(s0), dpp_f<0x4E>(s1), dpp_f<0x4E>(s2), dpp_f<0x4E>(s3));
    // L4: row_half_mirror
    MERGE4(dpp_f<0x141>(s0), dpp_f<0x141>(s1), dpp_f<0x141>(s2), dpp_f<0x141>(s3));
    // L8: row_mirror
    MERGE4(dpp_f<0x140>(s0), dpp_f<0x140>(s1), dpp_f<0x140>(s2), dpp_f<0x140>(s3));
    // L16: ds_swizzle xor16
    MERGE4(swz16(s0), swz16(s1), swz16(s2), swz16(s3));
    // L32: one LDS float4 exchange with lane^32 (intra-wave, fence only)
    sh_x[tid] = make_float4(s0, s1, s2, s3);
    asm volatile("" ::: "memory");
    {
        const float4 o = sh_x[tid ^ 32];
        MERGE4(o.x, o.y, o.z, o.w);
    }
    // now every lane holds the row's global sorted top-4 in s0..s3

    // ---- pass 2: recover indices from cached dds (exactly 4 hits/row) ----
#pragma unroll
    for (int k = 0; k < 16; ++k) {
        if (dd[k] <= s3) {                        // rare: ~4 of 1024 per row
            const int j = ((k >> 1) << 7) + (lane << 1) + (k & 1);
            const int rank = (int)(dd[k] > s0) + (int)(dd[k] > s1)
                           + (int)(dd[k] > s2);
            sh_idx[wv][rank] = j;
        }
    }
    asm volatile("" ::: "memory");                 // wave-private sh_idx

    // ---- per-wave epilogue: lanes 0..31 write this wave's row (128 B) ----
    if (lane < 32) {
        const int kk = lane >> 3;                  // neighbor rank 0..3
        const int e  = lane & 7;                   // embedding dim 0..7

        int j = sh_idx[wv][kk] & (NTR - 1);        // defensive in-bounds

        const float2 pj  = sh_pos[j];
        const float2* __restrict__ o1 = (const float2*)(obs1 + (size_t)batch * NTR * 2);
        const float2 o1j = o1[j];
        const float2 o1r = o1[i];
        const float f0 = pj.x - my.x;                       // rel_pos.x
        const float f1 = pj.y - my.y;                       // rel_pos.y
        const float f2 = (pj.x - o1j.x) - (my.x - o1r.x);   // rel_dir.x
        const float f3 = (pj.y - o1j.y) - (my.y - o1r.y);   // rel_dir.y

        const float4 w = ((const float4*)W)[e];
        float r = f0 * w.x + f1 * w.y + f2 * w.z + f3 * w.w + bias[e];
        r = fmaxf(r, 0.0f);

        out[(((size_t)(batch * NTR + i)) << 5) + lane] = r;
    }
}

extern "C" void kernel_launch(void* const* d_in, const int* in_sizes, int n_in,
                              void* d_out, int out_size, void* d_ws, size_t ws_size,
                              hipStream_t stream) {
    const float* obs1 = (const float*)d_in[0];
    const float* obs2 = (const float*)d_in[1];
    const float* W    = (const float*)d_in[2];
    const float* bias = (const float*)d_in[3];
    float* out = (float*)d_out;

    const int grid = BATCH * (NTR / 4);   // 2048 blocks, wave per row, 8/CU
    knn_v15<<<grid, 256, 0, stream>>>(obs1, obs2, W, bias, out);
}